// Round 1
// baseline (42.743 us; speedup 1.0000x reference)
//
#include <hip/hip_runtime.h>

// LIF/SNN forward: x [B,T,C,H,W] f32, thresh [1,C,1,1] f32 -> spikes [B,T,C,H,W] f32
// Recurrence per (b,c,h,w):
//   mem = mem*0.5 + x[t]; spike = (mem - thresh > 0); mem *= (1-spike)
//
// B=16 T=8 C=256 H=32 W=32. Memory-bound: 256 MiB total traffic -> ~41us roofline.

#define TDIM 8
#define TAU 0.5f

// per-b (no T) element counts, in float4 units (all powers of two -> shift math)
#define CHW4 65536   // 256*32*32/4
#define HW4  256     // 32*32/4
#define N4   1048576 // 16*256*32*32/4

__global__ __launch_bounds__(256) void lif_fwd_kernel(
    const float4* __restrict__ x, const float* __restrict__ thresh,
    float4* __restrict__ out)
{
    int i = blockIdx.x * blockDim.x + threadIdx.x;  // index over [B,C,H,W]/4
    if (i >= N4) return;

    int b    = i >> 16;          // i / CHW4
    int rest = i & (CHW4 - 1);   // i % CHW4
    int c    = rest >> 8;        // rest / HW4

    float th = thresh[c];

    size_t base = (size_t)b * (TDIM * (size_t)CHW4) + (size_t)rest;
    const float4* xp = x + base;
    float4*       op = out + base;

    float4 mem = make_float4(0.f, 0.f, 0.f, 0.f);

#pragma unroll
    for (int t = 0; t < TDIM; ++t) {
        float4 xt = xp[(size_t)t * CHW4];
        float4 s;
        mem.x = mem.x * TAU + xt.x; s.x = (mem.x > th) ? 1.f : 0.f; mem.x *= (1.f - s.x);
        mem.y = mem.y * TAU + xt.y; s.y = (mem.y > th) ? 1.f : 0.f; mem.y *= (1.f - s.y);
        mem.z = mem.z * TAU + xt.z; s.z = (mem.z > th) ? 1.f : 0.f; mem.z *= (1.f - s.z);
        mem.w = mem.w * TAU + xt.w; s.w = (mem.w > th) ? 1.f : 0.f; mem.w *= (1.f - s.w);
        op[(size_t)t * CHW4] = s;
    }
}

extern "C" void kernel_launch(void* const* d_in, const int* in_sizes, int n_in,
                              void* d_out, int out_size, void* d_ws, size_t ws_size,
                              hipStream_t stream)
{
    const float4* x      = (const float4*)d_in[0];
    const float*  thresh = (const float*)d_in[1];
    float4*       out    = (float4*)d_out;

    dim3 block(256);
    dim3 grid(N4 / 256);  // 4096 blocks
    lif_fwd_kernel<<<grid, block, 0, stream>>>(x, thresh, out);
}